// Round 9
// baseline (663.223 us; speedup 1.0000x reference)
//
#include <hip/hip_runtime.h>

// EntityLinker fused edge-MLP for MI355X (gfx950).
// Round 8b: R8 with compile fix — __builtin_nontemporal_load requires native
// vector types, so gathers use an ext_vector_type(4) float alias.
//   - Node gathers nontemporal (protect 320 KB weight set in per-XCD L2).
//   - Depth-2 ping-pong software pipeline in every rolled K-loop.
//   - M=128/block, 2 WG/CU, staged diff/prod, cheap cvt (R7 baseline).

#define H 128

typedef __bf16 bf16x8 __attribute__((ext_vector_type(8)));
typedef float f32x4 __attribute__((ext_vector_type(4)));
typedef float f32x4v __attribute__((ext_vector_type(4)));   // for nontemporal ld

__device__ __forceinline__ unsigned short f2bf(float f) {
    unsigned u = __builtin_bit_cast(unsigned, f);
    u += 0x7FFFu + ((u >> 16) & 1u);   // RNE (prep kernels only)
    return (unsigned short)(u >> 16);
}
__device__ __forceinline__ float bfhi(unsigned u) {
    return __builtin_bit_cast(float, u & 0xffff0000u);
}
__device__ __forceinline__ float bflo(unsigned u) {
    return __builtin_bit_cast(float, u << 16);
}
// pack two f32 -> bf16x2 (round-nearest-ties-away via +0x8000, v_perm pack)
__device__ __forceinline__ unsigned pk2(float r0, float r1) {
    unsigned u0 = __builtin_bit_cast(unsigned, r0) + 0x8000u;
    unsigned u1 = __builtin_bit_cast(unsigned, r1) + 0x8000u;
    return __builtin_amdgcn_perm(u1, u0, 0x07060302u);  // hi16(u1)<<16 | hi16(u0)
}
// |a-b| or a*b on packed bf16x2 -> packed bf16x2
__device__ __forceinline__ unsigned comb(unsigned ua, unsigned ub, bool isdiff) {
    float a0 = bflo(ua), a1 = bfhi(ua);
    float b0 = bflo(ub), b1 = bfhi(ub);
    float r0 = isdiff ? fabsf(a0 - b0) : a0 * b0;
    float r1 = isdiff ? fabsf(a1 - b1) : a1 * b1;
    return pk2(r0, r1);
}
__device__ __forceinline__ unsigned short cvt1(float v) {
    unsigned u = __builtin_bit_cast(unsigned, v) + 0x8000u;
    return (unsigned short)(u >> 16);
}

__global__ void prep_w1(const float* __restrict__ W1, unsigned short* __restrict__ W1T) {
    int idx = blockIdx.x * 256 + threadIdx.x;      // 131072
    int n = idx >> 9;
    int k = idx & 511;
    W1T[idx] = f2bf(W1[k * 256 + n]);              // W1 is [512][256] (in,out)
}

__global__ void prep_w2(const float* __restrict__ W2, unsigned short* __restrict__ W2T) {
    int idx = blockIdx.x * 256 + threadIdx.x;      // 32768
    int n = idx >> 8;
    int k = idx & 255;
    W2T[idx] = f2bf(W2[k * 128 + n]);              // W2 is [256][128]
}

__launch_bounds__(256, 2)
__global__ void fused_mlp(const float* __restrict__ node,
                          const int* __restrict__ src,
                          const int* __restrict__ dst,
                          const unsigned short* __restrict__ W1T,  // [256][512] bf16
                          const float* __restrict__ b1,
                          const unsigned short* __restrict__ W2T,  // [128][256] bf16
                          const float* __restrict__ b2,
                          const float* __restrict__ W3,            // [128][2] f32
                          const float* __restrict__ b3,
                          float* __restrict__ out,                 // [E][2] f32
                          int E) {
    // sH: [128][268] bf16. Region P (cols 0..127): hi, later diff.
    //                      Region Q (cols 136..263): hj, later prod.
    // Overlays: x1 [128][268] cols 0..255 after layer 1; x2 [128][140] after layer 2.
    __shared__ __align__(16) unsigned short sH[128 * 268];   // 68608 B
    __shared__ __align__(16) float sW3[256];                 // [c][128]

    const int t = threadIdx.x;
    const int e0 = blockIdx.x * 128;

    const int lane = t & 63;
    const int wv = t >> 6;
    const int quad = lane >> 4;
    const int lrow = lane & 15;
    const int nb = wv * 64;        // layer-1 N-slice
    const int nb2 = wv * 32;       // layer-2 N-slice

    // ---------------- Phase A: gather hi/hj -> LDS (nontemporal) ----------------
    {
        int r = t >> 1;            // edge row 0..127
        int p = t & 1;             // 64-col half
        int e = e0 + r;
        int ec = e < E ? e : (E - 1);
        const f32x4v* hi = (const f32x4v*)(node + (long)src[ec] * H + p * 64);
        const f32x4v* hj = (const f32x4v*)(node + (long)dst[ec] * H + p * 64);
        unsigned short* rowp = sH + r * 268;
#pragma unroll
        for (int b = 0; b < 16; b++) {
            f32x4v a = __builtin_nontemporal_load(hi + b);
            f32x4v c = __builtin_nontemporal_load(hj + b);
            int c0 = p * 64 + b * 4;
            uint2 wa, wc;
            wa.x = pk2(a.x, a.y); wa.y = pk2(a.z, a.w);
            wc.x = pk2(c.x, c.y); wc.y = pk2(c.z, c.w);
            *(uint2*)(rowp + c0)       = wa;
            *(uint2*)(rowp + 136 + c0) = wc;
        }
        sW3[(t & 1) * 128 + (t >> 1)] = W3[t];   // [k][c] -> [c][k]
    }
    __syncthreads();               // hi/hj visible

    // ---------------- Phase B: layer 1 (M=128, N=256, K=512) ----------------
    const unsigned short* w1p[4];
#pragma unroll
    for (int nt = 0; nt < 4; nt++) w1p[nt] = W1T + (nb + nt * 16 + lrow) * 512 + quad * 8;

    f32x4 acc[8][4];
#pragma unroll
    for (int mt = 0; mt < 8; mt++)
#pragma unroll
        for (int nt = 0; nt < 4; nt++)
            acc[mt][nt] = (f32x4){0.f, 0.f, 0.f, 0.f};

    int aoff[8];
#pragma unroll
    for (int mt = 0; mt < 8; mt++) aoff[mt] = (mt * 16 + lrow) * 268 + quad * 8;

    bf16x8 bvA[4], avA[8], bvB[4], avB[8];

    // ---- K-half 1: k 0..255 (A = hi | hj), ping-pong depth 2 ----
#pragma unroll
    for (int nt = 0; nt < 4; nt++) bvA[nt] = *(const bf16x8*)(w1p[nt]);
#pragma unroll
    for (int mt = 0; mt < 8; mt++) avA[mt] = *(const bf16x8*)(sH + aoff[mt]);

#pragma unroll 1
    for (int ks = 0; ks < 8; ks += 2) {
        const int k1 = ks + 1;                               // 1,3,5,7
        const int ao1 = (k1 < 4) ? k1 * 32 : 136 + (k1 - 4) * 32;
#pragma unroll
        for (int nt = 0; nt < 4; nt++) bvB[nt] = *(const bf16x8*)(w1p[nt] + k1 * 32);
#pragma unroll
        for (int mt = 0; mt < 8; mt++) avB[mt] = *(const bf16x8*)(sH + aoff[mt] + ao1);
#pragma unroll
        for (int mt = 0; mt < 8; mt++)
#pragma unroll
            for (int nt = 0; nt < 4; nt++)
                acc[mt][nt] = __builtin_amdgcn_mfma_f32_16x16x32_bf16(avA[mt], bvA[nt], acc[mt][nt], 0, 0, 0);
        const int k2 = (ks + 2 < 8) ? ks + 2 : 7;            // clamp: redundant last
        const int ao2 = (k2 < 4) ? k2 * 32 : 136 + (k2 - 4) * 32;
#pragma unroll
        for (int nt = 0; nt < 4; nt++) bvA[nt] = *(const bf16x8*)(w1p[nt] + k2 * 32);
#pragma unroll
        for (int mt = 0; mt < 8; mt++) avA[mt] = *(const bf16x8*)(sH + aoff[mt] + ao2);
#pragma unroll
        for (int mt = 0; mt < 8; mt++)
#pragma unroll
            for (int nt = 0; nt < 4; nt++)
                acc[mt][nt] = __builtin_amdgcn_mfma_f32_16x16x32_bf16(avB[mt], bvB[nt], acc[mt][nt], 0, 0, 0);
    }

    __syncthreads();               // half-1 reads of hi/hj complete

    // ------------- Staging: diff -> region P, prod -> region Q (in place) -------
    {
        int r = t >> 1;
        int c0 = (t & 1) * 64;
        unsigned short* rowp = sH + r * 268;
#pragma unroll
        for (int j = 0; j < 8; j++) {
            uint4 ua = *(const uint4*)(rowp + c0 + j * 8);
            uint4 ub = *(const uint4*)(rowp + 136 + c0 + j * 8);
            uint4 dd, pp;
            dd.x = comb(ua.x, ub.x, true);  dd.y = comb(ua.y, ub.y, true);
            dd.z = comb(ua.z, ub.z, true);  dd.w = comb(ua.w, ub.w, true);
            pp.x = comb(ua.x, ub.x, false); pp.y = comb(ua.y, ub.y, false);
            pp.z = comb(ua.z, ub.z, false); pp.w = comb(ua.w, ub.w, false);
            *(uint2*)(rowp + c0 + j * 8)           = (uint2){dd.x, dd.y};
            *(uint2*)(rowp + c0 + j * 8 + 4)       = (uint2){dd.z, dd.w};
            *(uint2*)(rowp + 136 + c0 + j * 8)     = (uint2){pp.x, pp.y};
            *(uint2*)(rowp + 136 + c0 + j * 8 + 4) = (uint2){pp.z, pp.w};
        }
    }
    __syncthreads();               // diff/prod staged

    // ---- K-half 2: k 256..511 (A = diff | prod), ping-pong depth 2 ----
#pragma unroll
    for (int nt = 0; nt < 4; nt++) bvA[nt] = *(const bf16x8*)(w1p[nt] + 8 * 32);
#pragma unroll
    for (int mt = 0; mt < 8; mt++) avA[mt] = *(const bf16x8*)(sH + aoff[mt]);

#pragma unroll 1
    for (int ks = 0; ks < 8; ks += 2) {
        const int k1 = ks + 1;
        const int ao1 = (k1 < 4) ? k1 * 32 : 136 + (k1 - 4) * 32;
#pragma unroll
        for (int nt = 0; nt < 4; nt++) bvB[nt] = *(const bf16x8*)(w1p[nt] + (k1 + 8) * 32);
#pragma unroll
        for (int mt = 0; mt < 8; mt++) avB[mt] = *(const bf16x8*)(sH + aoff[mt] + ao1);
#pragma unroll
        for (int mt = 0; mt < 8; mt++)
#pragma unroll
            for (int nt = 0; nt < 4; nt++)
                acc[mt][nt] = __builtin_amdgcn_mfma_f32_16x16x32_bf16(avA[mt], bvA[nt], acc[mt][nt], 0, 0, 0);
        const int k2 = (ks + 2 < 8) ? ks + 2 : 7;
        const int ao2 = (k2 < 4) ? k2 * 32 : 136 + (k2 - 4) * 32;
#pragma unroll
        for (int nt = 0; nt < 4; nt++) bvA[nt] = *(const bf16x8*)(w1p[nt] + (k2 + 8) * 32);
#pragma unroll
        for (int mt = 0; mt < 8; mt++) avA[mt] = *(const bf16x8*)(sH + aoff[mt] + ao2);
#pragma unroll
        for (int mt = 0; mt < 8; mt++)
#pragma unroll
            for (int nt = 0; nt < 4; nt++)
                acc[mt][nt] = __builtin_amdgcn_mfma_f32_16x16x32_bf16(avB[mt], bvB[nt], acc[mt][nt], 0, 0, 0);
    }

    // ---------------- Phase C: relu+bias -> x1 bf16 (overlay sH) ----------------
    float b1v[4];
#pragma unroll
    for (int nt = 0; nt < 4; nt++) b1v[nt] = b1[nb + nt * 16 + lrow];

    __syncthreads();               // all layer-1 reads of sH done
    unsigned short* sx1 = sH;      // [128][268], cols 0..255
#pragma unroll
    for (int mt = 0; mt < 8; mt++)
#pragma unroll
        for (int nt = 0; nt < 4; nt++)
#pragma unroll
            for (int i = 0; i < 4; i++) {
                int row = mt * 16 + quad * 4 + i;    // C/D: row = quad*4 + reg
                int col = nb + nt * 16 + lrow;       //      col = lane&15
                float v = acc[mt][nt][i] + b1v[nt];
                v = v > 0.f ? v : 0.f;
                sx1[row * 268 + col] = cvt1(v);
            }
    __syncthreads();               // x1 complete

    // ---------------- Phase D: layer 2 (M=128, N=128, K=256), ping-pong ---------
    const unsigned short* w2p[2];
#pragma unroll
    for (int nt = 0; nt < 2; nt++) w2p[nt] = W2T + (nb2 + nt * 16 + lrow) * 256 + quad * 8;

    f32x4 acc2[8][2];
#pragma unroll
    for (int mt = 0; mt < 8; mt++)
#pragma unroll
        for (int nt = 0; nt < 2; nt++)
            acc2[mt][nt] = (f32x4){0.f, 0.f, 0.f, 0.f};

#pragma unroll
    for (int nt = 0; nt < 2; nt++) bvA[nt] = *(const bf16x8*)(w2p[nt]);
#pragma unroll
    for (int mt = 0; mt < 8; mt++) avA[mt] = *(const bf16x8*)(sx1 + aoff[mt]);

#pragma unroll 1
    for (int ks = 0; ks < 8; ks += 2) {
        const int k1 = ks + 1;
#pragma unroll
        for (int nt = 0; nt < 2; nt++) bvB[nt] = *(const bf16x8*)(w2p[nt] + k1 * 32);
#pragma unroll
        for (int mt = 0; mt < 8; mt++) avB[mt] = *(const bf16x8*)(sx1 + aoff[mt] + k1 * 32);
#pragma unroll
        for (int mt = 0; mt < 8; mt++)
#pragma unroll
            for (int nt = 0; nt < 2; nt++)
                acc2[mt][nt] = __builtin_amdgcn_mfma_f32_16x16x32_bf16(avA[mt], bvA[nt], acc2[mt][nt], 0, 0, 0);
        const int k2 = (ks + 2 < 8) ? ks + 2 : 7;
#pragma unroll
        for (int nt = 0; nt < 2; nt++) bvA[nt] = *(const bf16x8*)(w2p[nt] + k2 * 32);
#pragma unroll
        for (int mt = 0; mt < 8; mt++) avA[mt] = *(const bf16x8*)(sx1 + aoff[mt] + k2 * 32);
#pragma unroll
        for (int mt = 0; mt < 8; mt++)
#pragma unroll
            for (int nt = 0; nt < 2; nt++)
                acc2[mt][nt] = __builtin_amdgcn_mfma_f32_16x16x32_bf16(avB[mt], bvB[nt], acc2[mt][nt], 0, 0, 0);
    }

    // ---------------- Phase E: relu+bias -> x2 bf16 (overlay) ----------------
    float b2v[2];
#pragma unroll
    for (int nt = 0; nt < 2; nt++) b2v[nt] = b2[nb2 + nt * 16 + lrow];

    __syncthreads();               // all layer-2 reads of x1 done
    unsigned short* sx2 = sH;      // [128][140] (70 dw stride, gcd 2 -> free)
#pragma unroll
    for (int mt = 0; mt < 8; mt++)
#pragma unroll
        for (int nt = 0; nt < 2; nt++)
#pragma unroll
            for (int i = 0; i < 4; i++) {
                int row = mt * 16 + quad * 4 + i;
                int col = nb2 + nt * 16 + lrow;
                float v = acc2[mt][nt][i] + b2v[nt];
                v = v > 0.f ? v : 0.f;
                sx2[row * 140 + col] = cvt1(v);
            }
    __syncthreads();

    // ---------------- Phase F: layer 3 (N=2), one thread per (row,class) ------
    {
        int r = t >> 1;            // edge row 0..127
        int c = t & 1;             // class
        const unsigned short* xr = sx2 + r * 140;
        const float* w3c = sW3 + c * 128;
        float s = 0.f;
#pragma unroll
        for (int j = 0; j < 16; j++) {
            uint4 v = *(const uint4*)(xr + j * 8);
            const float* w = w3c + j * 8;
            s += bflo(v.x) * w[0] + bfhi(v.x) * w[1]
               + bflo(v.y) * w[2] + bfhi(v.y) * w[3]
               + bflo(v.z) * w[4] + bfhi(v.z) * w[5]
               + bflo(v.w) * w[6] + bfhi(v.w) * w[7];
        }
        int e = e0 + r;
        if (e < E) __builtin_nontemporal_store(s + b3[c], &out[e * 2 + c]);
    }
}

extern "C" void kernel_launch(void* const* d_in, const int* in_sizes, int n_in,
                              void* d_out, int out_size, void* d_ws, size_t ws_size,
                              hipStream_t stream) {
    const float* node = (const float*)d_in[0];
    const int* src    = (const int*)d_in[1];
    const int* dst    = (const int*)d_in[2];
    const float* W1   = (const float*)d_in[3];
    const float* b1   = (const float*)d_in[4];
    const float* W2   = (const float*)d_in[5];
    const float* b2   = (const float*)d_in[6];
    const float* W3   = (const float*)d_in[7];
    const float* b3   = (const float*)d_in[8];
    float* out = (float*)d_out;
    const int E = in_sizes[1];

    unsigned short* W1T = (unsigned short*)d_ws;       // [256][512] bf16
    unsigned short* W2T = W1T + 512 * 256;             // [128][256] bf16

    hipLaunchKernelGGL(prep_w1, dim3(512), dim3(256), 0, stream, W1, W1T);
    hipLaunchKernelGGL(prep_w2, dim3(128), dim3(256), 0, stream, W2, W2T);
    const int nblk = (E + 127) / 128;
    hipLaunchKernelGGL(fused_mlp, dim3(nblk), dim3(256), 0, stream,
                       node, src, dst, W1T, b1, W2T, b2, W3, b3, out, E);
}

// Round 10
// 426.386 us; speedup vs baseline: 1.5555x; 1.5555x over previous
//
#include <hip/hip_runtime.h>

// EntityLinker fused edge-MLP for MI355X (gfx950).
// Round 10: attack the real bottleneck — random node-row gather traffic.
//   Diagnostic: dur tracks FETCH_SIZE (~1.5 us/MB) across R2..R8b while
//   compute restructures at constant FETCH moved nothing -> kernel is bound
//   by the L2-fill path of the 512B-granule random gather.
//   - prep_node: cast node_repr f32->bf16 once (25.6->12.8 MB in d_ws).
//     Gathered rows are 256B not 512B: dominant FETCH halves, L2 hit rate
//     doubles, phase A becomes pure uint4 copies (no cvt VALU).
//   - Plain cached loads (R8b's nontemporal hint destroyed ~10x node reuse).
//   - R7 structure otherwise: M=128/block, 2 WG/CU, staged diff/prod.

#define H 128

typedef __bf16 bf16x8 __attribute__((ext_vector_type(8)));
typedef float f32x4 __attribute__((ext_vector_type(4)));

__device__ __forceinline__ unsigned short f2bf(float f) {
    unsigned u = __builtin_bit_cast(unsigned, f);
    u += 0x7FFFu + ((u >> 16) & 1u);   // RNE
    return (unsigned short)(u >> 16);
}
__device__ __forceinline__ float bfhi(unsigned u) {
    return __builtin_bit_cast(float, u & 0xffff0000u);
}
__device__ __forceinline__ float bflo(unsigned u) {
    return __builtin_bit_cast(float, u << 16);
}
// pack two f32 -> bf16x2 (round-nearest-ties-away via +0x8000, v_perm pack)
__device__ __forceinline__ unsigned pk2(float r0, float r1) {
    unsigned u0 = __builtin_bit_cast(unsigned, r0) + 0x8000u;
    unsigned u1 = __builtin_bit_cast(unsigned, r1) + 0x8000u;
    return __builtin_amdgcn_perm(u1, u0, 0x07060302u);
}
// |a-b| or a*b on packed bf16x2 -> packed bf16x2
__device__ __forceinline__ unsigned comb(unsigned ua, unsigned ub, bool isdiff) {
    float a0 = bflo(ua), a1 = bfhi(ua);
    float b0 = bflo(ub), b1 = bfhi(ub);
    float r0 = isdiff ? fabsf(a0 - b0) : a0 * b0;
    float r1 = isdiff ? fabsf(a1 - b1) : a1 * b1;
    return pk2(r0, r1);
}
__device__ __forceinline__ unsigned short cvt1(float v) {
    unsigned u = __builtin_bit_cast(unsigned, v) + 0x8000u;
    return (unsigned short)(u >> 16);
}

__global__ void prep_node(const float* __restrict__ node, unsigned short* __restrict__ nbf) {
    int idx = blockIdx.x * 256 + threadIdx.x;      // 1.6M threads, 4 elems each
    const f32x4* p = (const f32x4*)(node) + idx;
    f32x4 v = *p;
    ushort4 w;
    w.x = f2bf(v.x); w.y = f2bf(v.y); w.z = f2bf(v.z); w.w = f2bf(v.w);
    *(ushort4*)(nbf + idx * 4) = w;
}

__global__ void prep_w1(const float* __restrict__ W1, unsigned short* __restrict__ W1T) {
    int idx = blockIdx.x * 256 + threadIdx.x;      // 131072
    int n = idx >> 9;
    int k = idx & 511;
    W1T[idx] = f2bf(W1[k * 256 + n]);              // W1 is [512][256] (in,out)
}

__global__ void prep_w2(const float* __restrict__ W2, unsigned short* __restrict__ W2T) {
    int idx = blockIdx.x * 256 + threadIdx.x;      // 32768
    int n = idx >> 8;
    int k = idx & 255;
    W2T[idx] = f2bf(W2[k * 128 + n]);              // W2 is [256][128]
}

__launch_bounds__(256, 2)
__global__ void fused_mlp(const unsigned short* __restrict__ nbf,   // [N][128] bf16
                          const int* __restrict__ src,
                          const int* __restrict__ dst,
                          const unsigned short* __restrict__ W1T,  // [256][512] bf16
                          const float* __restrict__ b1,
                          const unsigned short* __restrict__ W2T,  // [128][256] bf16
                          const float* __restrict__ b2,
                          const float* __restrict__ W3,            // [128][2] f32
                          const float* __restrict__ b3,
                          float* __restrict__ out,                 // [E][2] f32
                          int E) {
    // sH: [128][268] bf16. Region P (cols 0..127): hi, later diff.
    //                      Region Q (cols 136..263): hj, later prod.
    // Overlays: x1 [128][268] cols 0..255 after layer 1; x2 [128][140] after layer 2.
    __shared__ __align__(16) unsigned short sH[128 * 268];   // 68608 B
    __shared__ __align__(16) float sW3[256];                 // [c][128]

    const int t = threadIdx.x;
    const int e0 = blockIdx.x * 128;

    const int lane = t & 63;
    const int wv = t >> 6;
    const int quad = lane >> 4;
    const int lrow = lane & 15;
    const int nb = wv * 64;        // layer-1 N-slice
    const int nb2 = wv * 32;       // layer-2 N-slice

    // ---------------- Phase A: gather hi/hj (bf16) -> LDS, straight copy --------
    {
        int r = t >> 1;            // edge row 0..127
        int p = t & 1;             // 64-col half
        int e = e0 + r;
        int ec = e < E ? e : (E - 1);
        const unsigned short* hi = nbf + (long)src[ec] * H + p * 64;
        const unsigned short* hj = nbf + (long)dst[ec] * H + p * 64;
        unsigned short* rowp = sH + r * 268 + p * 64;
#pragma unroll
        for (int b = 0; b < 8; b++) {
            uint4 a = *(const uint4*)(hi + b * 8);
            uint4 c = *(const uint4*)(hj + b * 8);
            *(uint4*)(rowp + b * 8)       = a;
            *(uint4*)(rowp + 136 + b * 8) = c;
        }
        sW3[(t & 1) * 128 + (t >> 1)] = W3[t];   // [k][c] -> [c][k]
    }
    __syncthreads();               // hi/hj visible

    // ---------------- Phase B: layer 1 (M=128, N=256, K=512) ----------------
    const unsigned short* w1p[4];
#pragma unroll
    for (int nt = 0; nt < 4; nt++) w1p[nt] = W1T + (nb + nt * 16 + lrow) * 512 + quad * 8;

    f32x4 acc[8][4];
#pragma unroll
    for (int mt = 0; mt < 8; mt++)
#pragma unroll
        for (int nt = 0; nt < 4; nt++)
            acc[mt][nt] = (f32x4){0.f, 0.f, 0.f, 0.f};

    int aoff[8];
#pragma unroll
    for (int mt = 0; mt < 8; mt++) aoff[mt] = (mt * 16 + lrow) * 268 + quad * 8;

    // K-half 1: k 0..255  (A = hi | hj, as stored)
#pragma unroll 1
    for (int ks = 0; ks < 8; ks++) {
        const int ao = (ks < 4) ? ks * 32 : 136 + (ks - 4) * 32;
        bf16x8 bv[4], av[8];
#pragma unroll
        for (int nt = 0; nt < 4; nt++) bv[nt] = *(const bf16x8*)(w1p[nt] + ks * 32);
#pragma unroll
        for (int mt = 0; mt < 8; mt++) av[mt] = *(const bf16x8*)(sH + aoff[mt] + ao);
#pragma unroll
        for (int mt = 0; mt < 8; mt++)
#pragma unroll
            for (int nt = 0; nt < 4; nt++)
                acc[mt][nt] = __builtin_amdgcn_mfma_f32_16x16x32_bf16(av[mt], bv[nt], acc[mt][nt], 0, 0, 0);
    }

    __syncthreads();               // half-1 reads of hi/hj complete

    // ------------- Staging: diff -> region P, prod -> region Q (in place) -------
    {
        int r = t >> 1;
        int c0 = (t & 1) * 64;
        unsigned short* rowp = sH + r * 268;
#pragma unroll
        for (int j = 0; j < 8; j++) {
            uint4 ua = *(const uint4*)(rowp + c0 + j * 8);
            uint4 ub = *(const uint4*)(rowp + 136 + c0 + j * 8);
            uint4 dd, pp;
            dd.x = comb(ua.x, ub.x, true);  dd.y = comb(ua.y, ub.y, true);
            dd.z = comb(ua.z, ub.z, true);  dd.w = comb(ua.w, ub.w, true);
            pp.x = comb(ua.x, ub.x, false); pp.y = comb(ua.y, ub.y, false);
            pp.z = comb(ua.z, ub.z, false); pp.w = comb(ua.w, ub.w, false);
            *(uint2*)(rowp + c0 + j * 8)           = (uint2){dd.x, dd.y};
            *(uint2*)(rowp + c0 + j * 8 + 4)       = (uint2){dd.z, dd.w};
            *(uint2*)(rowp + 136 + c0 + j * 8)     = (uint2){pp.x, pp.y};
            *(uint2*)(rowp + 136 + c0 + j * 8 + 4) = (uint2){pp.z, pp.w};
        }
    }
    __syncthreads();               // diff/prod staged

    // K-half 2: k 256..511 (A = diff | prod, same addressing as half-1)
#pragma unroll 1
    for (int ks = 0; ks < 8; ks++) {
        const int ao = (ks < 4) ? ks * 32 : 136 + (ks - 4) * 32;
        bf16x8 bv[4], av[8];
#pragma unroll
        for (int nt = 0; nt < 4; nt++) bv[nt] = *(const bf16x8*)(w1p[nt] + (ks + 8) * 32);
#pragma unroll
        for (int mt = 0; mt < 8; mt++) av[mt] = *(const bf16x8*)(sH + aoff[mt] + ao);
#pragma unroll
        for (int mt = 0; mt < 8; mt++)
#pragma unroll
            for (int nt = 0; nt < 4; nt++)
                acc[mt][nt] = __builtin_amdgcn_mfma_f32_16x16x32_bf16(av[mt], bv[nt], acc[mt][nt], 0, 0, 0);
    }

    // ---------------- Phase C: relu+bias -> x1 bf16 (overlay sH) ----------------
    float b1v[4];
#pragma unroll
    for (int nt = 0; nt < 4; nt++) b1v[nt] = b1[nb + nt * 16 + lrow];

    __syncthreads();               // all layer-1 reads of sH done
    unsigned short* sx1 = sH;      // [128][268], cols 0..255
#pragma unroll
    for (int mt = 0; mt < 8; mt++)
#pragma unroll
        for (int nt = 0; nt < 4; nt++)
#pragma unroll
            for (int i = 0; i < 4; i++) {
                int row = mt * 16 + quad * 4 + i;    // C/D: row = quad*4 + reg
                int col = nb + nt * 16 + lrow;       //      col = lane&15
                float v = acc[mt][nt][i] + b1v[nt];
                v = v > 0.f ? v : 0.f;
                sx1[row * 268 + col] = cvt1(v);
            }
    __syncthreads();               // x1 complete

    // ---------------- Phase D: layer 2 (M=128, N=128, K=256) ----------------
    const unsigned short* w2p[2];
#pragma unroll
    for (int nt = 0; nt < 2; nt++) w2p[nt] = W2T + (nb2 + nt * 16 + lrow) * 256 + quad * 8;

    f32x4 acc2[8][2];
#pragma unroll
    for (int mt = 0; mt < 8; mt++)
#pragma unroll
        for (int nt = 0; nt < 2; nt++)
            acc2[mt][nt] = (f32x4){0.f, 0.f, 0.f, 0.f};

#pragma unroll 1
    for (int ks = 0; ks < 8; ks++) {
        bf16x8 bv2[2], av2[8];
#pragma unroll
        for (int nt = 0; nt < 2; nt++) bv2[nt] = *(const bf16x8*)(w2p[nt] + ks * 32);
#pragma unroll
        for (int mt = 0; mt < 8; mt++) av2[mt] = *(const bf16x8*)(sx1 + aoff[mt] + ks * 32);
#pragma unroll
        for (int mt = 0; mt < 8; mt++)
#pragma unroll
            for (int nt = 0; nt < 2; nt++)
                acc2[mt][nt] = __builtin_amdgcn_mfma_f32_16x16x32_bf16(av2[mt], bv2[nt], acc2[mt][nt], 0, 0, 0);
    }

    // ---------------- Phase E: relu+bias -> x2 bf16 (overlay) ----------------
    float b2v[2];
#pragma unroll
    for (int nt = 0; nt < 2; nt++) b2v[nt] = b2[nb2 + nt * 16 + lrow];

    __syncthreads();               // all layer-2 reads of x1 done
    unsigned short* sx2 = sH;      // [128][140] (70 dw stride, gcd 2 -> free)
#pragma unroll
    for (int mt = 0; mt < 8; mt++)
#pragma unroll
        for (int nt = 0; nt < 2; nt++)
#pragma unroll
            for (int i = 0; i < 4; i++) {
                int row = mt * 16 + quad * 4 + i;
                int col = nb2 + nt * 16 + lrow;
                float v = acc2[mt][nt][i] + b2v[nt];
                v = v > 0.f ? v : 0.f;
                sx2[row * 140 + col] = cvt1(v);
            }
    __syncthreads();

    // ---------------- Phase F: layer 3 (N=2), one thread per (row,class) ------
    {
        int r = t >> 1;            // edge row 0..127
        int c = t & 1;             // class
        const unsigned short* xr = sx2 + r * 140;
        const float* w3c = sW3 + c * 128;
        float s = 0.f;
#pragma unroll
        for (int j = 0; j < 16; j++) {
            uint4 v = *(const uint4*)(xr + j * 8);
            const float* w = w3c + j * 8;
            s += bflo(v.x) * w[0] + bfhi(v.x) * w[1]
               + bflo(v.y) * w[2] + bfhi(v.y) * w[3]
               + bflo(v.z) * w[4] + bfhi(v.z) * w[5]
               + bflo(v.w) * w[6] + bfhi(v.w) * w[7];
        }
        int e = e0 + r;
        if (e < E) out[e * 2 + c] = s + b3[c];
    }
}

extern "C" void kernel_launch(void* const* d_in, const int* in_sizes, int n_in,
                              void* d_out, int out_size, void* d_ws, size_t ws_size,
                              hipStream_t stream) {
    const float* node = (const float*)d_in[0];
    const int* src    = (const int*)d_in[1];
    const int* dst    = (const int*)d_in[2];
    const float* W1   = (const float*)d_in[3];
    const float* b1   = (const float*)d_in[4];
    const float* W2   = (const float*)d_in[5];
    const float* b2   = (const float*)d_in[6];
    const float* W3   = (const float*)d_in[7];
    const float* b3   = (const float*)d_in[8];
    float* out = (float*)d_out;
    const int NN = in_sizes[0] / H;                    // 50000 nodes
    const int E = in_sizes[1];

    unsigned short* W1T = (unsigned short*)d_ws;       // [256][512] bf16 = 256 KiB
    unsigned short* W2T = W1T + 512 * 256;             // [128][256] bf16 = 64 KiB
    unsigned short* NBF = W2T + 256 * 128;             // [50000][128] bf16 = 12.8 MB

    hipLaunchKernelGGL(prep_node, dim3((NN * H / 4 + 255) / 256), dim3(256), 0, stream, node, NBF);
    hipLaunchKernelGGL(prep_w1, dim3(512), dim3(256), 0, stream, W1, W1T);
    hipLaunchKernelGGL(prep_w2, dim3(128), dim3(256), 0, stream, W2, W2T);
    const int nblk = (E + 127) / 128;
    hipLaunchKernelGGL(fused_mlp, dim3(nblk), dim3(256), 0, stream,
                       NBF, src, dst, W1T, b1, W2T, b2, W3, b3, out, E);
}

// Round 11
// 419.337 us; speedup vs baseline: 1.5816x; 1.0168x over previous
//
#include <hip/hip_runtime.h>

// EntityLinker fused edge-MLP for MI355X (gfx950).
// Round 11: fragment-major weight packing — kill the 16-way scattered B-load.
//   R10 diagnosis: ~2000 cyc exposed latency per rolled K-iteration; each B
//   fragment load touched 16 cache lines 1KB apart (row-scatter across lanes).
//   Pack W1/W2 so a wave's fragment load is ONE contiguous 1KB block:
//     W1P[(g_nt*16+ks)][lane][8 bf16]  (wave-uniform base + lane*16B).
//   Main kernel otherwise identical to R10 (M=128/block, 2 WG/CU, bf16 node
//   cache in d_ws, staged diff/prod, cheap cvt).

#define H 128

typedef __bf16 bf16x8 __attribute__((ext_vector_type(8)));
typedef float f32x4 __attribute__((ext_vector_type(4)));

__device__ __forceinline__ unsigned short f2bf(float f) {
    unsigned u = __builtin_bit_cast(unsigned, f);
    u += 0x7FFFu + ((u >> 16) & 1u);   // RNE
    return (unsigned short)(u >> 16);
}
__device__ __forceinline__ float bfhi(unsigned u) {
    return __builtin_bit_cast(float, u & 0xffff0000u);
}
__device__ __forceinline__ float bflo(unsigned u) {
    return __builtin_bit_cast(float, u << 16);
}
__device__ __forceinline__ unsigned pk2(float r0, float r1) {
    unsigned u0 = __builtin_bit_cast(unsigned, r0) + 0x8000u;
    unsigned u1 = __builtin_bit_cast(unsigned, r1) + 0x8000u;
    return __builtin_amdgcn_perm(u1, u0, 0x07060302u);
}
__device__ __forceinline__ unsigned comb(unsigned ua, unsigned ub, bool isdiff) {
    float a0 = bflo(ua), a1 = bfhi(ua);
    float b0 = bflo(ub), b1 = bfhi(ub);
    float r0 = isdiff ? fabsf(a0 - b0) : a0 * b0;
    float r1 = isdiff ? fabsf(a1 - b1) : a1 * b1;
    return pk2(r0, r1);
}
__device__ __forceinline__ unsigned short cvt1(float v) {
    unsigned u = __builtin_bit_cast(unsigned, v) + 0x8000u;
    return (unsigned short)(u >> 16);
}

__global__ void prep_node(const float* __restrict__ node, unsigned short* __restrict__ nbf) {
    int idx = blockIdx.x * 256 + threadIdx.x;      // N*H/4 threads, 4 elems each
    const f32x4* p = (const f32x4*)(node) + idx;
    f32x4 v = *p;
    ushort4 w;
    w.x = f2bf(v.x); w.y = f2bf(v.y); w.z = f2bf(v.z); w.w = f2bf(v.w);
    *(ushort4*)(nbf + idx * 4) = w;
}

// Fragment-major pack of W1 [512][256] (in,out):
//   W1P[o], o = (g_nt*16 + ks)*512 + lane*8 + j
//   row = g_nt*16 + (lane&15), k = ks*32 + (lane>>4)*8 + j
__global__ void prep_w1(const float* __restrict__ W1, unsigned short* __restrict__ W1P) {
    int o = blockIdx.x * 256 + threadIdx.x;        // 131072
    int chunk = o >> 9;                            // 0..255 = g_nt*16 + ks
    int g_nt = chunk >> 4;
    int ks = chunk & 15;
    int r = o & 511;
    int lane = r >> 3;
    int j = r & 7;
    int row = g_nt * 16 + (lane & 15);
    int k = ks * 32 + (lane >> 4) * 8 + j;
    W1P[o] = f2bf(W1[k * 256 + row]);
}

// Fragment-major pack of W2 [256][128]:
//   W2P[o], o = (g_nt*8 + ks)*512 + lane*8 + j
//   row = g_nt*16 + (lane&15), k = ks*32 + (lane>>4)*8 + j
__global__ void prep_w2(const float* __restrict__ W2, unsigned short* __restrict__ W2P) {
    int o = blockIdx.x * 256 + threadIdx.x;        // 32768
    int chunk = o >> 9;                            // 0..63 = g_nt*8 + ks
    int g_nt = chunk >> 3;
    int ks = chunk & 7;
    int r = o & 511;
    int lane = r >> 3;
    int j = r & 7;
    int row = g_nt * 16 + (lane & 15);
    int k = ks * 32 + (lane >> 4) * 8 + j;
    W2P[o] = f2bf(W2[k * 128 + row]);
}

__launch_bounds__(256, 2)
__global__ void fused_mlp(const unsigned short* __restrict__ nbf,   // [N][128] bf16
                          const int* __restrict__ src,
                          const int* __restrict__ dst,
                          const unsigned short* __restrict__ W1P,  // packed, see prep_w1
                          const float* __restrict__ b1,
                          const unsigned short* __restrict__ W2P,  // packed, see prep_w2
                          const float* __restrict__ b2,
                          const float* __restrict__ W3,            // [128][2] f32
                          const float* __restrict__ b3,
                          float* __restrict__ out,                 // [E][2] f32
                          int E) {
    __shared__ __align__(16) unsigned short sH[128 * 268];   // 68608 B
    __shared__ __align__(16) float sW3[256];                 // [c][128]

    const int t = threadIdx.x;
    const int e0 = blockIdx.x * 128;

    const int lane = t & 63;
    const int wv = t >> 6;
    const int quad = lane >> 4;
    const int lrow = lane & 15;
    const int nb = wv * 64;        // layer-1 N-slice
    const int nb2 = wv * 32;       // layer-2 N-slice

    // ---------------- Phase A: gather hi/hj (bf16) -> LDS, straight copy --------
    {
        int r = t >> 1;            // edge row 0..127
        int p = t & 1;             // 64-col half
        int e = e0 + r;
        int ec = e < E ? e : (E - 1);
        const unsigned short* hi = nbf + (long)src[ec] * H + p * 64;
        const unsigned short* hj = nbf + (long)dst[ec] * H + p * 64;
        unsigned short* rowp = sH + r * 268 + p * 64;
#pragma unroll
        for (int b = 0; b < 8; b++) {
            uint4 a = *(const uint4*)(hi + b * 8);
            uint4 c = *(const uint4*)(hj + b * 8);
            *(uint4*)(rowp + b * 8)       = a;
            *(uint4*)(rowp + 136 + b * 8) = c;
        }
        sW3[(t & 1) * 128 + (t >> 1)] = W3[t];   // [k][c] -> [c][k]
    }
    __syncthreads();               // hi/hj visible

    // ---------------- Phase B: layer 1 (M=128, N=256, K=512) ----------------
    // Packed-B base: wave wv, n-tile nt -> g_nt = wv*4+nt; frag at
    //   W1P + (g_nt*16 + ks)*512 + lane*8   (contiguous 1KB per wave-load)
    const unsigned short* w1p[4];
#pragma unroll
    for (int nt = 0; nt < 4; nt++) w1p[nt] = W1P + (wv * 4 + nt) * 16 * 512 + lane * 8;

    f32x4 acc[8][4];
#pragma unroll
    for (int mt = 0; mt < 8; mt++)
#pragma unroll
        for (int nt = 0; nt < 4; nt++)
            acc[mt][nt] = (f32x4){0.f, 0.f, 0.f, 0.f};

    int aoff[8];
#pragma unroll
    for (int mt = 0; mt < 8; mt++) aoff[mt] = (mt * 16 + lrow) * 268 + quad * 8;

    // K-half 1: k 0..255  (A = hi | hj, as stored)
#pragma unroll 1
    for (int ks = 0; ks < 8; ks++) {
        const int ao = (ks < 4) ? ks * 32 : 136 + (ks - 4) * 32;
        bf16x8 bv[4], av[8];
#pragma unroll
        for (int nt = 0; nt < 4; nt++) bv[nt] = *(const bf16x8*)(w1p[nt] + ks * 512);
#pragma unroll
        for (int mt = 0; mt < 8; mt++) av[mt] = *(const bf16x8*)(sH + aoff[mt] + ao);
#pragma unroll
        for (int mt = 0; mt < 8; mt++)
#pragma unroll
            for (int nt = 0; nt < 4; nt++)
                acc[mt][nt] = __builtin_amdgcn_mfma_f32_16x16x32_bf16(av[mt], bv[nt], acc[mt][nt], 0, 0, 0);
    }

    __syncthreads();               // half-1 reads of hi/hj complete

    // ------------- Staging: diff -> region P, prod -> region Q (in place) -------
    {
        int r = t >> 1;
        int c0 = (t & 1) * 64;
        unsigned short* rowp = sH + r * 268;
#pragma unroll
        for (int j = 0; j < 8; j++) {
            uint4 ua = *(const uint4*)(rowp + c0 + j * 8);
            uint4 ub = *(const uint4*)(rowp + 136 + c0 + j * 8);
            uint4 dd, pp;
            dd.x = comb(ua.x, ub.x, true);  dd.y = comb(ua.y, ub.y, true);
            dd.z = comb(ua.z, ub.z, true);  dd.w = comb(ua.w, ub.w, true);
            pp.x = comb(ua.x, ub.x, false); pp.y = comb(ua.y, ub.y, false);
            pp.z = comb(ua.z, ub.z, false); pp.w = comb(ua.w, ub.w, false);
            *(uint2*)(rowp + c0 + j * 8)           = (uint2){dd.x, dd.y};
            *(uint2*)(rowp + c0 + j * 8 + 4)       = (uint2){dd.z, dd.w};
            *(uint2*)(rowp + 136 + c0 + j * 8)     = (uint2){pp.x, pp.y};
            *(uint2*)(rowp + 136 + c0 + j * 8 + 4) = (uint2){pp.z, pp.w};
        }
    }
    __syncthreads();               // diff/prod staged

    // K-half 2: k 256..511 (A = diff | prod, same addressing as half-1)
#pragma unroll 1
    for (int ks = 0; ks < 8; ks++) {
        const int ao = (ks < 4) ? ks * 32 : 136 + (ks - 4) * 32;
        bf16x8 bv[4], av[8];
#pragma unroll
        for (int nt = 0; nt < 4; nt++) bv[nt] = *(const bf16x8*)(w1p[nt] + (ks + 8) * 512);
#pragma unroll
        for (int mt = 0; mt < 8; mt++) av[mt] = *(const bf16x8*)(sH + aoff[mt] + ao);
#pragma unroll
        for (int mt = 0; mt < 8; mt++)
#pragma unroll
            for (int nt = 0; nt < 4; nt++)
                acc[mt][nt] = __builtin_amdgcn_mfma_f32_16x16x32_bf16(av[mt], bv[nt], acc[mt][nt], 0, 0, 0);
    }

    // ---------------- Phase C: relu+bias -> x1 bf16 (overlay sH) ----------------
    float b1v[4];
#pragma unroll
    for (int nt = 0; nt < 4; nt++) b1v[nt] = b1[nb + nt * 16 + lrow];

    __syncthreads();               // all layer-1 reads of sH done
    unsigned short* sx1 = sH;      // [128][268], cols 0..255
#pragma unroll
    for (int mt = 0; mt < 8; mt++)
#pragma unroll
        for (int nt = 0; nt < 4; nt++)
#pragma unroll
            for (int i = 0; i < 4; i++) {
                int row = mt * 16 + quad * 4 + i;    // C/D: row = quad*4 + reg
                int col = nb + nt * 16 + lrow;       //      col = lane&15
                float v = acc[mt][nt][i] + b1v[nt];
                v = v > 0.f ? v : 0.f;
                sx1[row * 268 + col] = cvt1(v);
            }
    __syncthreads();               // x1 complete

    // ---------------- Phase D: layer 2 (M=128, N=128, K=256) ----------------
    const unsigned short* w2p[2];
#pragma unroll
    for (int nt = 0; nt < 2; nt++) w2p[nt] = W2P + (wv * 2 + nt) * 8 * 512 + lane * 8;

    f32x4 acc2[8][2];
#pragma unroll
    for (int mt = 0; mt < 8; mt++)
#pragma unroll
        for (int nt = 0; nt < 2; nt++)
            acc2[mt][nt] = (f32x4){0.f, 0.f, 0.f, 0.f};

#pragma unroll 1
    for (int ks = 0; ks < 8; ks++) {
        bf16x8 bv2[2], av2[8];
#pragma unroll
        for (int nt = 0; nt < 2; nt++) bv2[nt] = *(const bf16x8*)(w2p[nt] + ks * 512);
#pragma unroll
        for (int mt = 0; mt < 8; mt++) av2[mt] = *(const bf16x8*)(sx1 + aoff[mt] + ks * 32);
#pragma unroll
        for (int mt = 0; mt < 8; mt++)
#pragma unroll
            for (int nt = 0; nt < 2; nt++)
                acc2[mt][nt] = __builtin_amdgcn_mfma_f32_16x16x32_bf16(av2[mt], bv2[nt], acc2[mt][nt], 0, 0, 0);
    }

    // ---------------- Phase E: relu+bias -> x2 bf16 (overlay) ----------------
    float b2v[2];
#pragma unroll
    for (int nt = 0; nt < 2; nt++) b2v[nt] = b2[nb2 + nt * 16 + lrow];

    __syncthreads();               // all layer-2 reads of x1 done
    unsigned short* sx2 = sH;      // [128][140] (70 dw stride, gcd 2 -> free)
#pragma unroll
    for (int mt = 0; mt < 8; mt++)
#pragma unroll
        for (int nt = 0; nt < 2; nt++)
#pragma unroll
            for (int i = 0; i < 4; i++) {
                int row = mt * 16 + quad * 4 + i;
                int col = nb2 + nt * 16 + lrow;
                float v = acc2[mt][nt][i] + b2v[nt];
                v = v > 0.f ? v : 0.f;
                sx2[row * 140 + col] = cvt1(v);
            }
    __syncthreads();

    // ---------------- Phase F: layer 3 (N=2), one thread per (row,class) ------
    {
        int r = t >> 1;            // edge row 0..127
        int c = t & 1;             // class
        const unsigned short* xr = sx2 + r * 140;
        const float* w3c = sW3 + c * 128;
        float s = 0.f;
#pragma unroll
        for (int j = 0; j < 16; j++) {
            uint4 v = *(const uint4*)(xr + j * 8);
            const float* w = w3c + j * 8;
            s += bflo(v.x) * w[0] + bfhi(v.x) * w[1]
               + bflo(v.y) * w[2] + bfhi(v.y) * w[3]
               + bflo(v.z) * w[4] + bfhi(v.z) * w[5]
               + bflo(v.w) * w[6] + bfhi(v.w) * w[7];
        }
        int e = e0 + r;
        if (e < E) out[e * 2 + c] = s + b3[c];
    }
}

extern "C" void kernel_launch(void* const* d_in, const int* in_sizes, int n_in,
                              void* d_out, int out_size, void* d_ws, size_t ws_size,
                              hipStream_t stream) {
    const float* node = (const float*)d_in[0];
    const int* src    = (const int*)d_in[1];
    const int* dst    = (const int*)d_in[2];
    const float* W1   = (const float*)d_in[3];
    const float* b1   = (const float*)d_in[4];
    const float* W2   = (const float*)d_in[5];
    const float* b2   = (const float*)d_in[6];
    const float* W3   = (const float*)d_in[7];
    const float* b3   = (const float*)d_in[8];
    float* out = (float*)d_out;
    const int NN = in_sizes[0] / H;                    // 50000 nodes
    const int E = in_sizes[1];

    unsigned short* W1P = (unsigned short*)d_ws;       // packed W1, 256 KiB
    unsigned short* W2P = W1P + 512 * 256;             // packed W2, 64 KiB
    unsigned short* NBF = W2P + 256 * 128;             // [N][128] bf16, 12.8 MB

    hipLaunchKernelGGL(prep_node, dim3((NN * H / 4 + 255) / 256), dim3(256), 0, stream, node, NBF);
    hipLaunchKernelGGL(prep_w1, dim3(512), dim3(256), 0, stream, W1, W1P);
    hipLaunchKernelGGL(prep_w2, dim3(128), dim3(256), 0, stream, W2, W2P);
    const int nblk = (E + 127) / 128;
    hipLaunchKernelGGL(fused_mlp, dim3(nblk), dim3(256), 0, stream,
                       NBF, src, dst, W1P, b1, W2P, b2, W3, b3, out, E);
}

// Round 12
// 382.578 us; speedup vs baseline: 1.7336x; 1.0961x over previous
//
#include <hip/hip_runtime.h>

// EntityLinker fused edge-MLP for MI355X (gfx950).
// Round 12: 3 independent blocks/CU (the stall-filler play).
//   R10/R11 falsified single-bottleneck theories: per-block wall ~47us vs
//   ~6us of work = many small exposed-latency chunks serialized by the
//   phase-barrier structure. Fix: more independent blocks to overlap them.
//   - M=64/block: acc=64 AGPRs + ~90 arch VGPRs ~ 155 unified < 170 cap of
//     __launch_bounds__(256,3) -> no spill (R5's spill was unrolled comb).
//   - LDS 34.8 KB -> 3 blocks = 104 KB of 160.
//   - Keeps: bf16 node cache, fragment-major packed weights (1KB coalesced
//     B-loads), staged in-place diff/prod, rolled K-loops, cheap cvt.

#define H 128

typedef __bf16 bf16x8 __attribute__((ext_vector_type(8)));
typedef float f32x4 __attribute__((ext_vector_type(4)));

__device__ __forceinline__ unsigned short f2bf(float f) {
    unsigned u = __builtin_bit_cast(unsigned, f);
    u += 0x7FFFu + ((u >> 16) & 1u);   // RNE
    return (unsigned short)(u >> 16);
}
__device__ __forceinline__ float bfhi(unsigned u) {
    return __builtin_bit_cast(float, u & 0xffff0000u);
}
__device__ __forceinline__ float bflo(unsigned u) {
    return __builtin_bit_cast(float, u << 16);
}
__device__ __forceinline__ unsigned pk2(float r0, float r1) {
    unsigned u0 = __builtin_bit_cast(unsigned, r0) + 0x8000u;
    unsigned u1 = __builtin_bit_cast(unsigned, r1) + 0x8000u;
    return __builtin_amdgcn_perm(u1, u0, 0x07060302u);
}
__device__ __forceinline__ unsigned comb(unsigned ua, unsigned ub, bool isdiff) {
    float a0 = bflo(ua), a1 = bfhi(ua);
    float b0 = bflo(ub), b1 = bfhi(ub);
    float r0 = isdiff ? fabsf(a0 - b0) : a0 * b0;
    float r1 = isdiff ? fabsf(a1 - b1) : a1 * b1;
    return pk2(r0, r1);
}
__device__ __forceinline__ unsigned short cvt1(float v) {
    unsigned u = __builtin_bit_cast(unsigned, v) + 0x8000u;
    return (unsigned short)(u >> 16);
}

__global__ void prep_node(const float* __restrict__ node, unsigned short* __restrict__ nbf) {
    int idx = blockIdx.x * 256 + threadIdx.x;      // N*H/4 threads, 4 elems each
    const f32x4* p = (const f32x4*)(node) + idx;
    f32x4 v = *p;
    ushort4 w;
    w.x = f2bf(v.x); w.y = f2bf(v.y); w.z = f2bf(v.z); w.w = f2bf(v.w);
    *(ushort4*)(nbf + idx * 4) = w;
}

// Fragment-major pack of W1 [512][256] (in,out):
//   W1P[o], o = (g_nt*16 + ks)*512 + lane*8 + j
//   row = g_nt*16 + (lane&15), k = ks*32 + (lane>>4)*8 + j
__global__ void prep_w1(const float* __restrict__ W1, unsigned short* __restrict__ W1P) {
    int o = blockIdx.x * 256 + threadIdx.x;        // 131072
    int chunk = o >> 9;
    int g_nt = chunk >> 4;
    int ks = chunk & 15;
    int r = o & 511;
    int lane = r >> 3;
    int j = r & 7;
    int row = g_nt * 16 + (lane & 15);
    int k = ks * 32 + (lane >> 4) * 8 + j;
    W1P[o] = f2bf(W1[k * 256 + row]);
}

// Fragment-major pack of W2 [256][128]:
//   W2P[o], o = (g_nt*8 + ks)*512 + lane*8 + j
__global__ void prep_w2(const float* __restrict__ W2, unsigned short* __restrict__ W2P) {
    int o = blockIdx.x * 256 + threadIdx.x;        // 32768
    int chunk = o >> 9;
    int g_nt = chunk >> 3;
    int ks = chunk & 7;
    int r = o & 511;
    int lane = r >> 3;
    int j = r & 7;
    int row = g_nt * 16 + (lane & 15);
    int k = ks * 32 + (lane >> 4) * 8 + j;
    W2P[o] = f2bf(W2[k * 128 + row]);
}

__launch_bounds__(256, 3)
__global__ void fused_mlp(const unsigned short* __restrict__ nbf,   // [N][128] bf16
                          const int* __restrict__ src,
                          const int* __restrict__ dst,
                          const unsigned short* __restrict__ W1P,  // packed
                          const float* __restrict__ b1,
                          const unsigned short* __restrict__ W2P,  // packed
                          const float* __restrict__ b2,
                          const float* __restrict__ W3,            // [128][2] f32
                          const float* __restrict__ b3,
                          float* __restrict__ out,                 // [E][2] f32
                          int E) {
    // sH: [64][268] bf16. Region P (cols 0..127): hi -> diff.
    //                     Region Q (cols 136..263): hj -> prod.
    // Overlays: x1 [64][268] cols 0..255; x2 [64][140].
    __shared__ __align__(16) unsigned short sH[64 * 268];    // 34304 B
    __shared__ __align__(16) float sW3[256];                 // [c][128]

    const int t = threadIdx.x;
    const int e0 = blockIdx.x * 64;

    const int lane = t & 63;
    const int wv = t >> 6;
    const int quad = lane >> 4;
    const int lrow = lane & 15;
    const int nb = wv * 64;        // layer-1 N-slice
    const int nb2 = wv * 32;       // layer-2 N-slice

    // ---------------- Phase A: gather hi/hj (bf16) -> LDS, line-granular --------
    {
        int r = t >> 2;            // edge row 0..63
        int q = t & 3;             // 32-col quarter (64 B = one cache line)
        int e = e0 + r;
        int ec = e < E ? e : (E - 1);
        const unsigned short* hi = nbf + (long)src[ec] * H + q * 32;
        const unsigned short* hj = nbf + (long)dst[ec] * H + q * 32;
        unsigned short* rowp = sH + r * 268 + q * 32;
#pragma unroll
        for (int b = 0; b < 4; b++) {
            uint4 a = *(const uint4*)(hi + b * 8);
            uint4 c = *(const uint4*)(hj + b * 8);
            *(uint4*)(rowp + b * 8)       = a;
            *(uint4*)(rowp + 136 + b * 8) = c;
        }
        sW3[(t & 1) * 128 + (t >> 1)] = W3[t];   // [k][c] -> [c][k]
    }
    __syncthreads();               // hi/hj visible

    // ---------------- Phase B: layer 1 (M=64, N=256, K=512) ----------------
    const unsigned short* w1p[4];
#pragma unroll
    for (int nt = 0; nt < 4; nt++) w1p[nt] = W1P + (wv * 4 + nt) * 16 * 512 + lane * 8;

    f32x4 acc[4][4];
#pragma unroll
    for (int mt = 0; mt < 4; mt++)
#pragma unroll
        for (int nt = 0; nt < 4; nt++)
            acc[mt][nt] = (f32x4){0.f, 0.f, 0.f, 0.f};

    int aoff[4];
#pragma unroll
    for (int mt = 0; mt < 4; mt++) aoff[mt] = (mt * 16 + lrow) * 268 + quad * 8;

    // K-half 1: k 0..255  (A = hi | hj, as stored)
#pragma unroll 1
    for (int ks = 0; ks < 8; ks++) {
        const int ao = (ks < 4) ? ks * 32 : 136 + (ks - 4) * 32;
        bf16x8 bv[4], av[4];
#pragma unroll
        for (int nt = 0; nt < 4; nt++) bv[nt] = *(const bf16x8*)(w1p[nt] + ks * 512);
#pragma unroll
        for (int mt = 0; mt < 4; mt++) av[mt] = *(const bf16x8*)(sH + aoff[mt] + ao);
#pragma unroll
        for (int mt = 0; mt < 4; mt++)
#pragma unroll
            for (int nt = 0; nt < 4; nt++)
                acc[mt][nt] = __builtin_amdgcn_mfma_f32_16x16x32_bf16(av[mt], bv[nt], acc[mt][nt], 0, 0, 0);
    }

    __syncthreads();               // half-1 reads of hi/hj complete

    // ------------- Staging: diff -> region P, prod -> region Q (in place) -------
    {
        int r = t >> 2;
        int c0 = (t & 3) * 32;
        unsigned short* rowp = sH + r * 268;
#pragma unroll
        for (int j = 0; j < 4; j++) {
            uint4 ua = *(const uint4*)(rowp + c0 + j * 8);
            uint4 ub = *(const uint4*)(rowp + 136 + c0 + j * 8);
            uint4 dd, pp;
            dd.x = comb(ua.x, ub.x, true);  dd.y = comb(ua.y, ub.y, true);
            dd.z = comb(ua.z, ub.z, true);  dd.w = comb(ua.w, ub.w, true);
            pp.x = comb(ua.x, ub.x, false); pp.y = comb(ua.y, ub.y, false);
            pp.z = comb(ua.z, ub.z, false); pp.w = comb(ua.w, ub.w, false);
            *(uint2*)(rowp + c0 + j * 8)           = (uint2){dd.x, dd.y};
            *(uint2*)(rowp + c0 + j * 8 + 4)       = (uint2){dd.z, dd.w};
            *(uint2*)(rowp + 136 + c0 + j * 8)     = (uint2){pp.x, pp.y};
            *(uint2*)(rowp + 136 + c0 + j * 8 + 4) = (uint2){pp.z, pp.w};
        }
    }
    __syncthreads();               // diff/prod staged

    // K-half 2: k 256..511 (A = diff | prod, same addressing)
#pragma unroll 1
    for (int ks = 0; ks < 8; ks++) {
        const int ao = (ks < 4) ? ks * 32 : 136 + (ks - 4) * 32;
        bf16x8 bv[4], av[4];
#pragma unroll
        for (int nt = 0; nt < 4; nt++) bv[nt] = *(const bf16x8*)(w1p[nt] + (ks + 8) * 512);
#pragma unroll
        for (int mt = 0; mt < 4; mt++) av[mt] = *(const bf16x8*)(sH + aoff[mt] + ao);
#pragma unroll
        for (int mt = 0; mt < 4; mt++)
#pragma unroll
            for (int nt = 0; nt < 4; nt++)
                acc[mt][nt] = __builtin_amdgcn_mfma_f32_16x16x32_bf16(av[mt], bv[nt], acc[mt][nt], 0, 0, 0);
    }

    // ---------------- Phase C: relu+bias -> x1 bf16 (overlay sH) ----------------
    float b1v[4];
#pragma unroll
    for (int nt = 0; nt < 4; nt++) b1v[nt] = b1[nb + nt * 16 + lrow];

    __syncthreads();               // all layer-1 reads of sH done
    unsigned short* sx1 = sH;      // [64][268], cols 0..255
#pragma unroll
    for (int mt = 0; mt < 4; mt++)
#pragma unroll
        for (int nt = 0; nt < 4; nt++)
#pragma unroll
            for (int i = 0; i < 4; i++) {
                int row = mt * 16 + quad * 4 + i;    // C/D: row = quad*4 + reg
                int col = nb + nt * 16 + lrow;       //      col = lane&15
                float v = acc[mt][nt][i] + b1v[nt];
                v = v > 0.f ? v : 0.f;
                sx1[row * 268 + col] = cvt1(v);
            }
    __syncthreads();               // x1 complete

    // ---------------- Phase D: layer 2 (M=64, N=128, K=256) ----------------
    const unsigned short* w2p[2];
#pragma unroll
    for (int nt = 0; nt < 2; nt++) w2p[nt] = W2P + (wv * 2 + nt) * 8 * 512 + lane * 8;

    f32x4 acc2[4][2];
#pragma unroll
    for (int mt = 0; mt < 4; mt++)
#pragma unroll
        for (int nt = 0; nt < 2; nt++)
            acc2[mt][nt] = (f32x4){0.f, 0.f, 0.f, 0.f};

#pragma unroll 1
    for (int ks = 0; ks < 8; ks++) {
        bf16x8 bv2[2], av2[4];
#pragma unroll
        for (int nt = 0; nt < 2; nt++) bv2[nt] = *(const bf16x8*)(w2p[nt] + ks * 512);
#pragma unroll
        for (int mt = 0; mt < 4; mt++) av2[mt] = *(const bf16x8*)(sx1 + aoff[mt] + ks * 32);
#pragma unroll
        for (int mt = 0; mt < 4; mt++)
#pragma unroll
            for (int nt = 0; nt < 2; nt++)
                acc2[mt][nt] = __builtin_amdgcn_mfma_f32_16x16x32_bf16(av2[mt], bv2[nt], acc2[mt][nt], 0, 0, 0);
    }

    // ---------------- Phase E: relu+bias -> x2 bf16 (overlay) ----------------
    float b2v[2];
#pragma unroll
    for (int nt = 0; nt < 2; nt++) b2v[nt] = b2[nb2 + nt * 16 + lrow];

    __syncthreads();               // all layer-2 reads of x1 done
    unsigned short* sx2 = sH;      // [64][140] (70 dw stride, gcd 2 -> free)
#pragma unroll
    for (int mt = 0; mt < 4; mt++)
#pragma unroll
        for (int nt = 0; nt < 2; nt++)
#pragma unroll
            for (int i = 0; i < 4; i++) {
                int row = mt * 16 + quad * 4 + i;
                int col = nb2 + nt * 16 + lrow;
                float v = acc2[mt][nt][i] + b2v[nt];
                v = v > 0.f ? v : 0.f;
                sx2[row * 140 + col] = cvt1(v);
            }
    __syncthreads();

    // ---------------- Phase F: layer 3 (N=2), half-dots + shfl ----------------
    {
        int r = t >> 2;            // edge row 0..63
        int c = t & 1;             // class
        int h = (t >> 1) & 1;      // K-half
        const unsigned short* xr = sx2 + r * 140 + h * 64;
        const float* w3c = sW3 + c * 128 + h * 64;
        float s = 0.f;
#pragma unroll
        for (int j = 0; j < 8; j++) {
            uint4 v = *(const uint4*)(xr + j * 8);
            const float* w = w3c + j * 8;
            s += bflo(v.x) * w[0] + bfhi(v.x) * w[1]
               + bflo(v.y) * w[2] + bfhi(v.y) * w[3]
               + bflo(v.z) * w[4] + bfhi(v.z) * w[5]
               + bflo(v.w) * w[6] + bfhi(v.w) * w[7];
        }
        s += __shfl_xor(s, 2);     // combine K-halves
        int e = e0 + r;
        if (h == 0 && e < E) out[e * 2 + c] = s + b3[c];
    }
}

extern "C" void kernel_launch(void* const* d_in, const int* in_sizes, int n_in,
                              void* d_out, int out_size, void* d_ws, size_t ws_size,
                              hipStream_t stream) {
    const float* node = (const float*)d_in[0];
    const int* src    = (const int*)d_in[1];
    const int* dst    = (const int*)d_in[2];
    const float* W1   = (const float*)d_in[3];
    const float* b1   = (const float*)d_in[4];
    const float* W2   = (const float*)d_in[5];
    const float* b2   = (const float*)d_in[6];
    const float* W3   = (const float*)d_in[7];
    const float* b3   = (const float*)d_in[8];
    float* out = (float*)d_out;
    const int NN = in_sizes[0] / H;                    // 50000 nodes
    const int E = in_sizes[1];

    unsigned short* W1P = (unsigned short*)d_ws;       // packed W1, 256 KiB
    unsigned short* W2P = W1P + 512 * 256;             // packed W2, 64 KiB
    unsigned short* NBF = W2P + 256 * 128;             // [N][128] bf16, 12.8 MB

    hipLaunchKernelGGL(prep_node, dim3((NN * H / 4 + 255) / 256), dim3(256), 0, stream, node, NBF);
    hipLaunchKernelGGL(prep_w1, dim3(512), dim3(256), 0, stream, W1, W1P);
    hipLaunchKernelGGL(prep_w2, dim3(128), dim3(256), 0, stream, W2, W2P);
    const int nblk = (E + 63) / 64;
    hipLaunchKernelGGL(fused_mlp, dim3(nblk), dim3(256), 0, stream,
                       NBF, src, dst, W1P, b1, W2P, b2, W3, b3, out, E);
}